// Round 8
// baseline (113.229 us; speedup 1.0000x reference)
//
#include <hip/hip_runtime.h>

// Problem constants (match reference)
#define C_DIM 16
#define R_DIM 1024
#define T_DIM 4096
#define TABLE (C_DIM * T_DIM)     // 65536 slots
#define REP 8                     // scatter-table replicas (kept identical to R7)

typedef float f32x4 __attribute__((ext_vector_type(4)));

// R8 = R7 byte-identical, plus the resolve_write node launched TWICE.
// Second pass rewrites identical values (deterministic, output unchanged).
// dur_R8 - dur_R7 == marginal cost of one full write phase. Pure ablation probe.

__global__ void scatter_max2(const int2* __restrict__ rho2,
                             const int2* __restrict__ theta2,
                             const int2* __restrict__ f2,
                             const int* __restrict__ rho,
                             const int* __restrict__ theta,
                             const int* __restrict__ f,
                             int* __restrict__ maxrho,
                             int rep_mask, int n) {
    int* table = maxrho + (blockIdx.x & rep_mask) * TABLE;
    int n2 = n >> 1;
    int i = blockIdx.x * blockDim.x + threadIdx.x;
    if (i < n2) {
        int2 rh = rho2[i], th = theta2[i], ff = f2[i];
        atomicMax(&table[ff.x * T_DIM + th.x], rh.x);
        atomicMax(&table[ff.y * T_DIM + th.y], rh.y);
    }
    if (i == 0 && (n & 1)) {
        int k = n - 1;
        atomicMax(&table[f[k] * T_DIM + theta[k]], rho[k]);
    }
}

__global__ __launch_bounds__(256) void resolve_write(
        const int* __restrict__ maxrho, int rep,
        const float* __restrict__ rp,
        const float* __restrict__ r,
        float* __restrict__ out) {
    const int c   = blockIdx.x >> 5;
    const int t0  = ((blockIdx.x >> 3) & 3) * 1024;
    const int rr0 = (blockIdx.x & 7) * 128;
    const int off = c * T_DIM + t0 + 4 * threadIdx.x;

    int4 m = *reinterpret_cast<const int4*>(maxrho + off);
    for (int q = 1; q < rep; ++q) {
        int4 mq = *reinterpret_cast<const int4*>(maxrho + q * TABLE + off);
        m.x = max(m.x, mq.x); m.y = max(m.y, mq.y);
        m.z = max(m.z, mq.z); m.w = max(m.w, mq.w);
    }

    f32x4 v;
    v.x = rp[m.x < 0 ? R_DIM : m.x];
    v.y = rp[m.y < 0 ? R_DIM : m.y];
    v.z = rp[m.z < 0 ? R_DIM : m.z];
    v.w = rp[m.w < 0 ? R_DIM : m.w];

    float* base = out + ((size_t)(c * R_DIM + rr0)) * T_DIM + t0 + 4 * threadIdx.x;

#pragma unroll 4
    for (int j = 0; j < 128; ++j) {
        float rv = r[rr0 + j];                  // wave-uniform scalar load
        f32x4 o = v - rv;
        *reinterpret_cast<f32x4*>(base + (size_t)j * T_DIM) = o;
    }
}

extern "C" void kernel_launch(void* const* d_in, const int* in_sizes, int n_in,
                              void* d_out, int out_size, void* d_ws, size_t ws_size,
                              hipStream_t stream) {
    const int*   rho   = (const int*)d_in[0];
    const int*   theta = (const int*)d_in[1];
    const int*   f     = (const int*)d_in[2];
    const float* rp    = (const float*)d_in[3];
    const float* r     = (const float*)d_in[4];
    float* out = (float*)d_out;

    int* maxrho = (int*)d_ws;
    const int n = in_sizes[0];

    const int rep = (ws_size >= (size_t)REP * TABLE * sizeof(int)) ? REP : 1;

    // 1. maxrho[rep] = -1 (0xFF bytes)
    hipMemsetAsync(maxrho, 0xFF, (size_t)rep * TABLE * sizeof(int), stream);

    // 2. replicated scatter atomicMax
    {
        int n2 = n >> 1;
        int blocks = (n2 + 255) / 256;
        scatter_max2<<<blocks, 256, 0, stream>>>(
            (const int2*)rho, (const int2*)theta, (const int2*)f,
            rho, theta, f, maxrho, rep - 1, n);
    }

    // 3. write phase — launched TWICE (ablation probe; second pass overwrites
    //    identical values, so output is unchanged and deterministic).
    resolve_write<<<512, 256, 0, stream>>>(maxrho, rep, rp, r, out);
    resolve_write<<<512, 256, 0, stream>>>(maxrho, rep, rp, r, out);
}

// Round 9
// 93.952 us; speedup vs baseline: 1.2052x; 1.2052x over previous
//
#include <hip/hip_runtime.h>

// Problem constants (match reference)
#define C_DIM 16
#define R_DIM 1024
#define T_DIM 4096
#define TABLE (C_DIM * T_DIM)     // 65536 slots
#define REP 8                     // one table per XCD

typedef float f32x4 __attribute__((ext_vector_type(4)));

// R9 = R7 + an ADDITIONAL scatter pass using workgroup-scope atomicMax into
// the XCD-private replica selected by HW_REG_XCC_ID. max is idempotent and
// commutative, so running both scatters into the same 8 tables leaves the
// replica-max unchanged -> output identical. dur_R9 - dur_R7 isolates the
// scoped-scatter cost.

__global__ void scatter_max2(const int2* __restrict__ rho2,
                             const int2* __restrict__ theta2,
                             const int2* __restrict__ f2,
                             const int* __restrict__ rho,
                             const int* __restrict__ theta,
                             const int* __restrict__ f,
                             int* __restrict__ maxrho,
                             int rep_mask, int n) {
    int* table = maxrho + (blockIdx.x & rep_mask) * TABLE;
    int n2 = n >> 1;
    int i = blockIdx.x * blockDim.x + threadIdx.x;
    if (i < n2) {
        int2 rh = rho2[i], th = theta2[i], ff = f2[i];
        atomicMax(&table[ff.x * T_DIM + th.x], rh.x);
        atomicMax(&table[ff.y * T_DIM + th.y], rh.y);
    }
    if (i == 0 && (n & 1)) {
        int k = n - 1;
        atomicMax(&table[f[k] * T_DIM + theta[k]], rho[k]);
    }
}

// Scoped scatter: replica = physical XCD id; workgroup-scope atomicMax should
// execute in the local XCD L2 (no cross-XCD coherence needed since the table
// is XCD-private by construction). End-of-dispatch L2 writeback publishes it.
__global__ void scatter_max2_wg(const int2* __restrict__ rho2,
                                const int2* __restrict__ theta2,
                                const int2* __restrict__ f2,
                                const int* __restrict__ rho,
                                const int* __restrict__ theta,
                                const int* __restrict__ f,
                                int* __restrict__ maxrho, int n) {
    unsigned xcc;
    asm volatile("s_getreg_b32 %0, hwreg(HW_REG_XCC_ID)" : "=s"(xcc));
    int* table = maxrho + (xcc & (REP - 1)) * TABLE;
    int n2 = n >> 1;
    int i = blockIdx.x * blockDim.x + threadIdx.x;
    if (i < n2) {
        int2 rh = rho2[i], th = theta2[i], ff = f2[i];
        __hip_atomic_fetch_max(&table[ff.x * T_DIM + th.x], rh.x,
                               __ATOMIC_RELAXED, __HIP_MEMORY_SCOPE_WORKGROUP);
        __hip_atomic_fetch_max(&table[ff.y * T_DIM + th.y], rh.y,
                               __ATOMIC_RELAXED, __HIP_MEMORY_SCOPE_WORKGROUP);
    }
    if (i == 0 && (n & 1)) {
        int k = n - 1;
        __hip_atomic_fetch_max(&table[f[k] * T_DIM + theta[k]], rho[k],
                               __ATOMIC_RELAXED, __HIP_MEMORY_SCOPE_WORKGROUP);
    }
}

__global__ __launch_bounds__(256) void resolve_write(
        const int* __restrict__ maxrho, int rep,
        const float* __restrict__ rp,
        const float* __restrict__ r,
        float* __restrict__ out) {
    const int c   = blockIdx.x >> 5;
    const int t0  = ((blockIdx.x >> 3) & 3) * 1024;
    const int rr0 = (blockIdx.x & 7) * 128;
    const int off = c * T_DIM + t0 + 4 * threadIdx.x;

    int4 m = *reinterpret_cast<const int4*>(maxrho + off);
    for (int q = 1; q < rep; ++q) {
        int4 mq = *reinterpret_cast<const int4*>(maxrho + q * TABLE + off);
        m.x = max(m.x, mq.x); m.y = max(m.y, mq.y);
        m.z = max(m.z, mq.z); m.w = max(m.w, mq.w);
    }

    f32x4 v;
    v.x = rp[m.x < 0 ? R_DIM : m.x];
    v.y = rp[m.y < 0 ? R_DIM : m.y];
    v.z = rp[m.z < 0 ? R_DIM : m.z];
    v.w = rp[m.w < 0 ? R_DIM : m.w];

    float* base = out + ((size_t)(c * R_DIM + rr0)) * T_DIM + t0 + 4 * threadIdx.x;

#pragma unroll 4
    for (int j = 0; j < 128; ++j) {
        float rv = r[rr0 + j];                  // wave-uniform scalar load
        f32x4 o = v - rv;
        *reinterpret_cast<f32x4*>(base + (size_t)j * T_DIM) = o;
    }
}

extern "C" void kernel_launch(void* const* d_in, const int* in_sizes, int n_in,
                              void* d_out, int out_size, void* d_ws, size_t ws_size,
                              hipStream_t stream) {
    const int*   rho   = (const int*)d_in[0];
    const int*   theta = (const int*)d_in[1];
    const int*   f     = (const int*)d_in[2];
    const float* rp    = (const float*)d_in[3];
    const float* r     = (const float*)d_in[4];
    float* out = (float*)d_out;

    int* maxrho = (int*)d_ws;
    const int n = in_sizes[0];

    const int rep = (ws_size >= (size_t)REP * TABLE * sizeof(int)) ? REP : 1;

    // 1. maxrho[rep] = -1 (0xFF bytes)
    hipMemsetAsync(maxrho, 0xFF, (size_t)rep * TABLE * sizeof(int), stream);

    const int n2 = n >> 1;
    const int blocks = (n2 + 255) / 256;

    // 2a. device-scope scatter (R7 baseline, unchanged)
    scatter_max2<<<blocks, 256, 0, stream>>>(
        (const int2*)rho, (const int2*)theta, (const int2*)f,
        rho, theta, f, maxrho, rep - 1, n);

    // 2b. ADDED probe: workgroup-scope scatter into XCC-private replica.
    //     Idempotent w.r.t. 2a -> output unchanged; marginal dur = its cost.
    if (rep == REP) {
        scatter_max2_wg<<<blocks, 256, 0, stream>>>(
            (const int2*)rho, (const int2*)theta, (const int2*)f,
            rho, theta, f, maxrho, n);
    }

    // 3. fused replica-max + resolve + streamed output
    resolve_write<<<512, 256, 0, stream>>>(maxrho, rep, rp, r, out);
}